// Round 1
// 256.463 us; speedup vs baseline: 1.0566x; 1.0566x over previous
//
#include <hip/hip_runtime.h>
#include <hip/hip_bf16.h>

// Problem constants
#define B_  2
#define S_  2048
#define D_  1024
#define H_  16
#define HD_ 64
#define M_  4096   // B_*S_

// Inputs/outputs f32; internal compute bf16 MFMA with f32 accumulation.
// ws (32 MB + 12 KB):
//   [0,8)MB  q bf16 (CE-prescaled via WTq/biasf; attn in-place)
//   [8,16)MB kb bf16
//   [16,24)MB WT bf16: 4 x [1024][1024] ([q CE*g | k g | v g | o plain])
//   [24,32)MB xhat bf16 [4096][1024]  (LN(data), affine folded into WT/biasf)
//   +32MB: biasf f32[3][1024]
// d_out (16 MB f32) as scratch until the final GEMM:
//   [0,8)MB vT bf16 [bh][d][s]   [8,16)MB kT bf16 [bh][d][s]
// gemm_out reads q + WT[o] (ws), writes d_out directly (vT/kT dead).
//
// attn_fused (this round): 32x32x16 MFMA, swapped operands (S^T / O^T,
// col = q = lane&31). P and the phase-0 q-update stay entirely in
// registers via pk2bf + v_permlane32_swap_b32 (T12) -- no P LDS
// round-trip. K/V tiles in plain [64][64] LDS with XOR swizzle
// (col ^= (row&7)<<3 shorts) -> conflict-free b128 access (T2).
// Softmax denominator via ones-A MFMA into lacc (all 16 regs = row sum).

typedef __attribute__((ext_vector_type(8))) short short8;
typedef __attribute__((ext_vector_type(4))) float f32x4;
typedef __attribute__((ext_vector_type(16))) float f32x16;

#define CE_ 0.1803368801111204f   // 0.125 * log2(e)

typedef __attribute__((address_space(1))) const unsigned GU;
typedef __attribute__((address_space(3))) unsigned LU;
static __device__ __forceinline__ void glds16(const void* g, void* l){
  __builtin_amdgcn_global_load_lds((GU*)g, (LU*)l, 16, 0, 0);
}

static __device__ __forceinline__ unsigned short f2bfc(float f){
  union{float f; unsigned u;} c; c.f = f;
  return (unsigned short)((c.u + 0x8000u) >> 16);
}
static __device__ __forceinline__ unsigned pk2bf(float a, float b){
  union{float f; unsigned u;} ca, cb; ca.f=a; cb.f=b;
  return __builtin_amdgcn_perm(cb.u + 0x8000u, ca.u + 0x8000u, 0x07060302u);
}
static __device__ __forceinline__ unsigned pk2bft(float a, float b){
  union{float f; unsigned u;} ca, cb; ca.f=a; cb.f=b;
  return __builtin_amdgcn_perm(cb.u, ca.u, 0x07060302u);
}
static __device__ __forceinline__ short8 mk8(unsigned x0, unsigned x1,
                                             unsigned x2, unsigned x3){
  union{ unsigned u[4]; short8 s; } t;
  t.u[0]=x0; t.u[1]=x1; t.u[2]=x2; t.u[3]=x3; return t.s;
}
// v_permlane32_swap_b32: new_x[32:63] = old_y[0:31]; new_y[0:31] = old_x[32:63]
static __device__ __forceinline__ void plswap(unsigned &x, unsigned &y){
  auto r = __builtin_amdgcn_permlane32_swap(x, y, false, false);
  x = (unsigned)r[0]; y = (unsigned)r[1];
}

// ---------------------------------------------------------------------------
// Merged prep: [0,1024) wtrans ; [1024,2048) xhat (stats+normalize fused,
// one row per wave) ; [2048,2096) biasfold.
// ---------------------------------------------------------------------------
__global__ __launch_bounds__(256) void prep_kernel(
  const float* __restrict__ data,
  const float* __restrict__ Wq, const float* __restrict__ Wk,
  const float* __restrict__ Wv, const float* __restrict__ Wo,
  const float* __restrict__ gq, const float* __restrict__ gk, const float* __restrict__ gv,
  const float* __restrict__ blq, const float* __restrict__ blk, const float* __restrict__ blv,
  const float* __restrict__ bpq, const float* __restrict__ bpk, const float* __restrict__ bpv,
  unsigned short* __restrict__ WT, unsigned short* __restrict__ xhat,
  float* __restrict__ bf)
{
  __shared__ unsigned short tile[64][72];
  __shared__ float red[4][64];
  int bid = blockIdx.x, t = threadIdx.x;
  if (bid < 1024){
    // --- weight transpose + cast: WT[z][n][k] = scale_z[k] * W_z[k][n] ---
    int z = bid >> 8, rem = bid & 255;
    int k0 = (rem>>4)*64, n0 = (rem&15)*64;
    const float* W = (z==0)?Wq:(z==1)?Wk:(z==2)?Wv:Wo;
    const float* g = (z==0)?gq:(z==1)?gk:(z==2)?gv:(const float*)0;
    unsigned short* out = WT + ((size_t)z<<20);
    {
      int kr = t>>2, c16 = (t&3)*16;
      float gs = g ? g[k0+kr]*((z==0)?CE_:1.0f) : 1.0f;
      const float* src = W + (size_t)(k0+kr)*D_ + n0 + c16;
      float4 w0 = *(const float4*)(src);
      float4 w1 = *(const float4*)(src+4);
      float4 w2 = *(const float4*)(src+8);
      float4 w3 = *(const float4*)(src+12);
      unsigned* tp = (unsigned*)&tile[kr][c16];
      tp[0]=pk2bf(w0.x*gs,w0.y*gs); tp[1]=pk2bf(w0.z*gs,w0.w*gs);
      tp[2]=pk2bf(w1.x*gs,w1.y*gs); tp[3]=pk2bf(w1.z*gs,w1.w*gs);
      tp[4]=pk2bf(w2.x*gs,w2.y*gs); tp[5]=pk2bf(w2.z*gs,w2.w*gs);
      tp[6]=pk2bf(w3.x*gs,w3.y*gs); tp[7]=pk2bf(w3.z*gs,w3.w*gs);
    }
    __syncthreads();
    {
      int nr = t>>2, kc = (t&3)*16;
      union { uint4 v[2]; unsigned short u[16]; } st;
      #pragma unroll
      for (int i=0;i<16;i++) st.u[i] = tile[kc+i][nr];
      unsigned short* dst = out + (size_t)(n0+nr)*D_ + k0 + kc;
      *(uint4*)(dst)     = st.v[0];
      *(uint4*)(dst + 8) = st.v[1];
    }
  } else if (bid < 2048){
    // --- xhat: one row per wave, stats + normalize + bf16 store ---
    int row = (bid-1024)*4 + (t>>6);
    int l = t & 63;
    const float4* xr = (const float4*)(data + (size_t)row*D_);
    float4 v[4];
    float s = 0.f, ss = 0.f;
    #pragma unroll
    for (int i=0;i<4;i++){
      v[i] = xr[l + 64*i];
      s  += v[i].x+v[i].y+v[i].z+v[i].w;
      ss += v[i].x*v[i].x+v[i].y*v[i].y+v[i].z*v[i].z+v[i].w*v[i].w;
    }
    #pragma unroll
    for (int m=1;m<64;m<<=1){ s += __shfl_xor(s, m, 64); ss += __shfl_xor(ss, m, 64); }
    float me = s*(1.0f/D_);
    float var = ss*(1.0f/D_) - me*me;
    float rs = rsqrtf(var + 1e-5f);
    float nm = -me*rs;
    unsigned short* xo = xhat + (size_t)row*D_;
    #pragma unroll
    for (int i=0;i<4;i++){
      uint2 pk;
      pk.x = pk2bf(fmaf(v[i].x,rs,nm), fmaf(v[i].y,rs,nm));
      pk.y = pk2bf(fmaf(v[i].z,rs,nm), fmaf(v[i].w,rs,nm));
      *(uint2*)(xo + 4*l + 256*i) = pk;
    }
  } else {
    // --- folded bias ---
    int idx = bid - 2048;
    int z = idx >> 4, xb = idx & 15;
    const float* W  = (z==0)?Wq:(z==1)?Wk:Wv;
    const float* bl = (z==0)?blq:(z==1)?blk:blv;
    const float* bp = (z==0)?bpq:(z==1)?bpk:bpv;
    int nl = t & 63, kg = t >> 6;
    int n = xb*64 + nl;
    float acc = 0.f;
    for (int k = kg*256; k < (kg+1)*256; k++)
      acc += bl[k] * W[(size_t)k*D_ + n];
    red[kg][nl] = acc;
    __syncthreads();
    if (t < 64){
      int nn = xb*64 + t;
      float v = red[0][t]+red[1][t]+red[2][t]+red[3][t] + bp[nn];
      bf[z*D_ + nn] = (z==0) ? v*CE_ : v;
    }
  }
}

// ---------------------------------------------------------------------------
// Fused QKV GEMM, grid (32,8,3). 128x128 tile. Both tiles via glds width=16
// (A from precomputed bf16 xhat), unpadded stride-32 LDS.
// ---------------------------------------------------------------------------
__global__ __launch_bounds__(256) void gemm_qkv(
  const unsigned short* __restrict__ xhat,
  const unsigned short* __restrict__ WT,
  const float* __restrict__ biasf,
  unsigned short* __restrict__ qv, unsigned short* __restrict__ kb,
  unsigned short* __restrict__ kT, unsigned short* __restrict__ vT)
{
  int z = blockIdx.z;
  const unsigned short* Bt = WT + ((size_t)z<<20);
  const float* bias = biasf + z*D_;
  unsigned short* oN = (z==0)?qv:(z==1)?kb:(unsigned short*)0;
  unsigned short* oT = (z==0)?(unsigned short*)0:(z==1)?kT:vT;

  __shared__ __align__(16) unsigned short As[128*32];
  __shared__ __align__(16) unsigned short Bs[128*32];
  int tid = threadIdx.x, w = tid>>6, l = tid&63;
  int m0 = blockIdx.x*128, n0 = blockIdx.y*128;
  int wr = (w>>1)*64, wc = (w&1)*64;
  int lr = l&15, qd = l>>4;

  const unsigned short* gA = xhat + (size_t)(m0 + w*32 + (l>>2))*D_ + (l&3)*8;
  const unsigned short* gB = Bt   + (size_t)(n0 + w*32 + (l>>2))*D_ + (l&3)*8;
  unsigned short* lA0 = &As[(w*32)*32];
  unsigned short* lA1 = &As[(w*32+16)*32];
  unsigned short* lB0 = &Bs[(w*32)*32];
  unsigned short* lB1 = &Bs[(w*32+16)*32];

  const f32x4 fz = {0.f,0.f,0.f,0.f};
  f32x4 acc[4][4];
  #pragma unroll
  for (int i=0;i<4;i++)
    #pragma unroll
    for (int j=0;j<4;j++) acc[i][j] = fz;

  for (int kk=0; kk<D_; kk+=32){
    __syncthreads();
    glds16(gA + kk,                 lA0);
    glds16(gA + kk + (size_t)16*D_, lA1);
    glds16(gB + kk,                 lB0);
    glds16(gB + kk + (size_t)16*D_, lB1);
    __syncthreads();
    short8 af[4], bfr[4];
    #pragma unroll
    for (int i=0;i<4;i++) af[i]  = *(const short8*)(As + (wr + i*16 + lr)*32 + qd*8);
    #pragma unroll
    for (int j=0;j<4;j++) bfr[j] = *(const short8*)(Bs + (wc + j*16 + lr)*32 + qd*8);
    #pragma unroll
    for (int i=0;i<4;i++)
      #pragma unroll
      for (int j=0;j<4;j++)
        acc[i][j] = __builtin_amdgcn_mfma_f32_16x16x32_bf16(af[i], bfr[j], acc[i][j], 0, 0, 0);
  }

  #pragma unroll
  for (int j=0;j<4;j++){
    int n = n0 + wc + j*16 + lr;
    float bias_n = bias[n];
    #pragma unroll
    for (int i=0;i<4;i++){
      int mb = m0 + wr + i*16 + qd*4;
      float v0 = acc[i][j][0] + bias_n;
      float v1 = acc[i][j][1] + bias_n;
      float v2 = acc[i][j][2] + bias_n;
      float v3 = acc[i][j][3] + bias_n;
      if (oN){
        oN[(size_t)(mb+0)*D_ + n] = f2bfc(v0);
        oN[(size_t)(mb+1)*D_ + n] = f2bfc(v1);
        oN[(size_t)(mb+2)*D_ + n] = f2bfc(v2);
        oN[(size_t)(mb+3)*D_ + n] = f2bfc(v3);
      }
      if (oT){
        int bb = mb >> 11, sI = mb & (S_-1);
        int hh = n >> 6,  dd = n & 63;
        uint2 pk; pk.x = pk2bf(v0, v1); pk.y = pk2bf(v2, v3);
        *(uint2*)(oT + (size_t)((bb*H_ + hh)*HD_ + dd)*S_ + sI) = pk;
      }
    }
  }
}

// ---------------------------------------------------------------------------
// Out-projection: C = A(bf16) @ WTo^T + bo, f32 to d_out. Both tiles via glds.
// ---------------------------------------------------------------------------
__global__ __launch_bounds__(256) void gemm_out(
  const unsigned short* __restrict__ A,
  const unsigned short* __restrict__ Bt,
  const float* __restrict__ bo,
  float* __restrict__ Cf)
{
  __shared__ __align__(16) unsigned short As[128*32];
  __shared__ __align__(16) unsigned short Bs[128*32];
  int tid = threadIdx.x, w = tid>>6, l = tid&63;
  int m0 = blockIdx.x*128, n0 = blockIdx.y*128;
  int wr = (w>>1)*64, wc = (w&1)*64;
  int lr = l&15, qd = l>>4;

  const unsigned short* gA = A  + (size_t)(m0 + w*32 + (l>>2))*D_ + (l&3)*8;
  const unsigned short* gB = Bt + (size_t)(n0 + w*32 + (l>>2))*D_ + (l&3)*8;
  unsigned short* lA0 = &As[(w*32)*32];
  unsigned short* lA1 = &As[(w*32+16)*32];
  unsigned short* lB0 = &Bs[(w*32)*32];
  unsigned short* lB1 = &Bs[(w*32+16)*32];

  const f32x4 fz = {0.f,0.f,0.f,0.f};
  f32x4 acc[4][4];
  #pragma unroll
  for (int i=0;i<4;i++)
    #pragma unroll
    for (int j=0;j<4;j++) acc[i][j] = fz;

  for (int kk=0; kk<D_; kk+=32){
    __syncthreads();
    glds16(gA + kk,                 lA0);
    glds16(gA + kk + (size_t)16*D_, lA1);
    glds16(gB + kk,                 lB0);
    glds16(gB + kk + (size_t)16*D_, lB1);
    __syncthreads();
    short8 af[4], bfr[4];
    #pragma unroll
    for (int i=0;i<4;i++) af[i]  = *(const short8*)(As + (wr + i*16 + lr)*32 + qd*8);
    #pragma unroll
    for (int j=0;j<4;j++) bfr[j] = *(const short8*)(Bs + (wc + j*16 + lr)*32 + qd*8);
    #pragma unroll
    for (int i=0;i<4;i++)
      #pragma unroll
      for (int j=0;j<4;j++)
        acc[i][j] = __builtin_amdgcn_mfma_f32_16x16x32_bf16(af[i], bfr[j], acc[i][j], 0, 0, 0);
  }

  #pragma unroll
  for (int j=0;j<4;j++){
    int n = n0 + wc + j*16 + lr;
    float bias_n = bo[n];
    #pragma unroll
    for (int i=0;i<4;i++){
      int mb = m0 + wr + i*16 + qd*4;
      Cf[(size_t)(mb+0)*D_ + n] = acc[i][j][0] + bias_n;
      Cf[(size_t)(mb+1)*D_ + n] = acc[i][j][1] + bias_n;
      Cf[(size_t)(mb+2)*D_ + n] = acc[i][j][2] + bias_n;
      Cf[(size_t)(mb+3)*D_ + n] = acc[i][j][3] + bias_n;
    }
  }
}

// ---------------------------------------------------------------------------
// Fused double Hopfield attention, 32x32x16 swapped-operand version.
// grid (32,16), 256 threads (4 waves x 32 q-rows = 128 q-rows/block).
// sK [64 s][64 d], sV [64 d][64 s], both XOR-swizzled (col ^= (row&7)<<3).
// P / q-update fully in registers via pk2bf + permlane32_swap.
// Row-sum (softmax denom) via ones-A MFMA into lacc.
// ---------------------------------------------------------------------------
__global__ __launch_bounds__(256) void attn_fused(
  unsigned short* __restrict__ QO,
  const unsigned short* __restrict__ K,
  const unsigned short* __restrict__ KT,
  const unsigned short* __restrict__ VT)
{
  int qt = blockIdx.x;           // 0..31
  int h  = blockIdx.y;           // 0..15
  int b  = qt >> 4;
  int bh = b*H_ + h;
  int tid = threadIdx.x, w = tid>>6, l = tid&63;
  int lq = l & 31;               // q column within wave tile (C col = q)
  int hi = l >> 5;               // k-half for A/B fragments
  int r8 = tid>>3, c8 = (tid&7)*8;   // staging: row 0..31(+32), col in shorts
  int swzw = (r8&7)<<3;              // write swizzle (shorts)
  int swzr = (lq&7)<<3;              // read swizzle (shorts), row = lq (+32)

  __shared__ __align__(16) unsigned short sK[64*64];   // [s][d]
  __shared__ __align__(16) unsigned short sV[64*64];   // [d][s]

  const f32x16 fz16 = {0.f,0.f,0.f,0.f,0.f,0.f,0.f,0.f,
                       0.f,0.f,0.f,0.f,0.f,0.f,0.f,0.f};
  const short8 ones = {(short)0x3F80,(short)0x3F80,(short)0x3F80,(short)0x3F80,
                       (short)0x3F80,(short)0x3F80,(short)0x3F80,(short)0x3F80};

  // Q fragments: B[k=d][col=q], k = hi*8+i, frag d-range = ds*16
  const unsigned short* Qb = QO + (size_t)(qt*128 + w*32 + lq)*D_ + h*64;
  short8 qf[4];
  #pragma unroll
  for (int d=0; d<4; d++)
    qf[d] = *(const short8*)(Qb + d*16 + hi*8);

  const unsigned short* Khead = K + (size_t)(b*S_)*D_ + h*64;
  const unsigned short* Vh0 = KT + (size_t)bh*HD_*S_;
  const unsigned short* Vh1 = VT + (size_t)bh*HD_*S_;

  uint4 kr0, kr1, vr0, vr1;
  kr0 = *(const uint4*)(Khead + (size_t)(r8   )*D_ + c8);
  kr1 = *(const uint4*)(Khead + (size_t)(r8+32)*D_ + c8);
  vr0 = *(const uint4*)(Vh0 + (size_t)(r8   )*S_ + c8);
  vr1 = *(const uint4*)(Vh0 + (size_t)(r8+32)*S_ + c8);

  #pragma unroll 1
  for (int phase=0; phase<2; phase++){
    const unsigned short* Vhead = phase ? Vh1 : Vh0;
    f32x16 oacc0 = fz16, oacc1 = fz16, lacc = fz16;

    for (int kt=0; kt<S_; kt+=64){
      __syncthreads();
      *(uint4*)(&sK[(size_t)(r8   )*64 + (c8 ^ swzw)]) = kr0;
      *(uint4*)(&sK[(size_t)(r8+32)*64 + (c8 ^ swzw)]) = kr1;
      *(uint4*)(&sV[(size_t)(r8   )*64 + (c8 ^ swzw)]) = vr0;
      *(uint4*)(&sV[(size_t)(r8+32)*64 + (c8 ^ swzw)]) = vr1;
      __syncthreads();

      {
        int nkt = kt + 64;
        const unsigned short* Vn = Vhead;
        if (nkt >= S_){ nkt = 0; Vn = Vh1; }
        kr0 = *(const uint4*)(Khead + (size_t)(nkt+r8   )*D_ + c8);
        kr1 = *(const uint4*)(Khead + (size_t)(nkt+r8+32)*D_ + c8);
        vr0 = *(const uint4*)(Vn + (size_t)(r8   )*S_ + nkt + c8);
        vr1 = *(const uint4*)(Vn + (size_t)(r8+32)*S_ + nkt + c8);
      }

      // --- QK^T: S^T[s][q], two 32-row s-tiles, accumulate over d ---
      f32x16 sc0 = fz16, sc1 = fz16;
      #pragma unroll
      for (int ds_=0; ds_<4; ds_++){
        short8 ka0 = *(const short8*)(&sK[(size_t)(lq   )*64 + ((ds_*16 + hi*8) ^ swzr)]);
        short8 ka1 = *(const short8*)(&sK[(size_t)(lq+32)*64 + ((ds_*16 + hi*8) ^ swzr)]);
        sc0 = __builtin_amdgcn_mfma_f32_32x32x16_bf16(ka0, qf[ds_], sc0, 0,0,0);
        sc1 = __builtin_amdgcn_mfma_f32_32x32x16_bf16(ka1, qf[ds_], sc1, 0,0,0);
      }

      // --- exp2 + in-register P->B-frag conversion (T12) ---
      float p0[16], p1[16];
      #pragma unroll
      for (int i=0;i<16;i++){
        p0[i] = __builtin_amdgcn_exp2f(sc0[i]);
        p1[i] = __builtin_amdgcn_exp2f(sc1[i]);
      }
      short8 pf[4];
      {
        unsigned a0,a1,b0,b1;
        a0=pk2bft(p0[0],p0[1]);   a1=pk2bft(p0[2],p0[3]);
        b0=pk2bft(p0[4],p0[5]);   b1=pk2bft(p0[6],p0[7]);
        plswap(a0,b0); plswap(a1,b1);
        pf[0] = mk8(a0,a1,b0,b1);
        a0=pk2bft(p0[8],p0[9]);   a1=pk2bft(p0[10],p0[11]);
        b0=pk2bft(p0[12],p0[13]); b1=pk2bft(p0[14],p0[15]);
        plswap(a0,b0); plswap(a1,b1);
        pf[1] = mk8(a0,a1,b0,b1);
        a0=pk2bft(p1[0],p1[1]);   a1=pk2bft(p1[2],p1[3]);
        b0=pk2bft(p1[4],p1[5]);   b1=pk2bft(p1[6],p1[7]);
        plswap(a0,b0); plswap(a1,b1);
        pf[2] = mk8(a0,a1,b0,b1);
        a0=pk2bft(p1[8],p1[9]);   a1=pk2bft(p1[10],p1[11]);
        b0=pk2bft(p1[12],p1[13]); b1=pk2bft(p1[14],p1[15]);
        plswap(a0,b0); plswap(a1,b1);
        pf[3] = mk8(a0,a1,b0,b1);
      }

      // --- PV: O^T[d][q] += V^T-tile x P ; denom via ones-MFMA ---
      #pragma unroll
      for (int ks=0; ks<4; ks++){
        short8 va0 = *(const short8*)(&sV[(size_t)(lq   )*64 + ((ks*16 + hi*8) ^ swzr)]);
        short8 va1 = *(const short8*)(&sV[(size_t)(lq+32)*64 + ((ks*16 + hi*8) ^ swzr)]);
        oacc0 = __builtin_amdgcn_mfma_f32_32x32x16_bf16(va0, pf[ks], oacc0, 0,0,0);
        oacc1 = __builtin_amdgcn_mfma_f32_32x32x16_bf16(va1, pf[ks], oacc1, 0,0,0);
        lacc  = __builtin_amdgcn_mfma_f32_32x32x16_bf16(ones, pf[ks], lacc, 0,0,0);
      }
    } // kt

    if (phase==0){
      // q <- (xi K) * CE, converted to B-frags in-register
      float iv = CE_ * __builtin_amdgcn_rcpf(lacc[0]);
      unsigned a0,a1,b0,b1;
      a0=pk2bf(oacc0[0]*iv, oacc0[1]*iv);   a1=pk2bf(oacc0[2]*iv, oacc0[3]*iv);
      b0=pk2bf(oacc0[4]*iv, oacc0[5]*iv);   b1=pk2bf(oacc0[6]*iv, oacc0[7]*iv);
      plswap(a0,b0); plswap(a1,b1);
      qf[0] = mk8(a0,a1,b0,b1);
      a0=pk2bf(oacc0[8]*iv, oacc0[9]*iv);   a1=pk2bf(oacc0[10]*iv, oacc0[11]*iv);
      b0=pk2bf(oacc0[12]*iv, oacc0[13]*iv); b1=pk2bf(oacc0[14]*iv, oacc0[15]*iv);
      plswap(a0,b0); plswap(a1,b1);
      qf[1] = mk8(a0,a1,b0,b1);
      a0=pk2bf(oacc1[0]*iv, oacc1[1]*iv);   a1=pk2bf(oacc1[2]*iv, oacc1[3]*iv);
      b0=pk2bf(oacc1[4]*iv, oacc1[5]*iv);   b1=pk2bf(oacc1[6]*iv, oacc1[7]*iv);
      plswap(a0,b0); plswap(a1,b1);
      qf[2] = mk8(a0,a1,b0,b1);
      a0=pk2bf(oacc1[8]*iv, oacc1[9]*iv);   a1=pk2bf(oacc1[10]*iv, oacc1[11]*iv);
      b0=pk2bf(oacc1[12]*iv, oacc1[13]*iv); b1=pk2bf(oacc1[14]*iv, oacc1[15]*iv);
      plswap(a0,b0); plswap(a1,b1);
      qf[3] = mk8(a0,a1,b0,b1);
    } else {
      float iv = __builtin_amdgcn_rcpf(lacc[0]);
      // C row = (r&3)+8*(r>>2)+4*hi -> d = dt*32 + g*8 + hi*4 + {0..3}
      unsigned short* Ob = QO + (size_t)(qt*128 + w*32 + lq)*D_ + h*64 + hi*4;
      #pragma unroll
      for (int g=0; g<4; g++){
        uint2 pk;
        pk.x = pk2bf(oacc0[4*g+0]*iv, oacc0[4*g+1]*iv);
        pk.y = pk2bf(oacc0[4*g+2]*iv, oacc0[4*g+3]*iv);
        *(uint2*)(Ob + g*8) = pk;
        pk.x = pk2bf(oacc1[4*g+0]*iv, oacc1[4*g+1]*iv);
        pk.y = pk2bf(oacc1[4*g+2]*iv, oacc1[4*g+3]*iv);
        *(uint2*)(Ob + 32 + g*8) = pk;
      }
    }
  } // phase
}

// ---------------------------------------------------------------------------
extern "C" void kernel_launch(void* const* d_in, const int* in_sizes, int n_in,
                              void* d_out, int out_size, void* d_ws, size_t ws_size,
                              hipStream_t stream){
  const float* data = (const float*)d_in[0];
  const float* g_k  = (const float*)d_in[1];
  const float* b_k  = (const float*)d_in[2];
  const float* g_q  = (const float*)d_in[3];
  const float* b_q  = (const float*)d_in[4];
  const float* g_v  = (const float*)d_in[5];
  const float* b_v  = (const float*)d_in[6];
  const float* Wq   = (const float*)d_in[7];
  const float* bq   = (const float*)d_in[8];
  const float* Wk   = (const float*)d_in[9];
  const float* bk   = (const float*)d_in[10];
  const float* Wv   = (const float*)d_in[11];
  const float* bv   = (const float*)d_in[12];
  const float* Wo   = (const float*)d_in[13];
  const float* bo   = (const float*)d_in[14];
  float* out = (float*)d_out;

  char* ws = (char*)d_ws;
  const size_t MB = (size_t)1<<20;
  unsigned short* q    = (unsigned short*)(ws);
  unsigned short* kb   = (unsigned short*)(ws + 8*MB);
  unsigned short* WT   = (unsigned short*)(ws + 16*MB);
  unsigned short* WTo  = WT + ((size_t)3<<20);
  unsigned short* xhat = (unsigned short*)(ws + 24*MB);
  float*          bfld = (float*)(ws + 32*MB);
  unsigned short* vT   = (unsigned short*)d_out;
  unsigned short* kT   = (unsigned short*)((char*)d_out + 8*MB);

  dim3 gb(256);
  prep_kernel<<<dim3(2096), gb, 0, stream>>>(data,
                                             Wq, Wk, Wv, Wo, g_q, g_k, g_v,
                                             b_q, b_k, b_v, bq, bk, bv,
                                             WT, xhat, bfld);
  gemm_qkv<<<dim3(32,8,3), gb, 0, stream>>>(xhat, WT, bfld, q, kb, kT, vT);
  attn_fused<<<dim3(32, H_), gb, 0, stream>>>(q, kb, kT, vT);
  gemm_out<<<dim3(32,8), gb, 0, stream>>>(q, WTo, bo, out);
}

// Round 2
// 251.871 us; speedup vs baseline: 1.0759x; 1.0182x over previous
//
#include <hip/hip_runtime.h>
#include <hip/hip_bf16.h>

// Problem constants
#define B_  2
#define S_  2048
#define D_  1024
#define H_  16
#define HD_ 64
#define M_  4096   // B_*S_

// Inputs/outputs f32; internal compute bf16 MFMA with f32 accumulation.
// ws (32 MB + 12 KB):
//   [0,8)MB  q bf16 (CE-prescaled via WTq/biasf; attn in-place)
//   [8,16)MB kb bf16
//   [16,24)MB WT bf16: 4 x [1024][1024] ([q CE*g | k g | v g | o plain])
//   [24,32)MB xhat bf16 [4096][1024]  (LN(data), affine folded into WT/biasf)
//   +32MB: biasf f32[3][1024]
// d_out (16 MB f32) as scratch until the final GEMM:
//   [0,8)MB vT bf16 [bh][d][s]   [8,16)MB kT bf16 [bh][d][s]
//
// attn_fused (this round): kt-split occupancy doubling. Grid (64,16),
// 4 blocks/CU (16 waves/CU). Wave (wq,wk): wq = q-subtile (32 rows),
// wk = kt half. Staging via global_load_lds with PRE-SWIZZLED global
// source (LDS dest linear, XOR involution on source col). Partial
// oacc/den combined across wk pairs through LDS at phase boundaries;
// phase-0 q-update shared via LDS. Denominator via VALU tree (no
// ones-MFMA) to stay <=128 VGPR for launch_bounds(256,4).

typedef __attribute__((ext_vector_type(8))) short short8;
typedef __attribute__((ext_vector_type(4))) float f32x4;
typedef __attribute__((ext_vector_type(16))) float f32x16;

#define CE_ 0.1803368801111204f   // 0.125 * log2(e)

typedef __attribute__((address_space(1))) const unsigned GU;
typedef __attribute__((address_space(3))) unsigned LU;
static __device__ __forceinline__ void glds16(const void* g, void* l){
  __builtin_amdgcn_global_load_lds((GU*)g, (LU*)l, 16, 0, 0);
}

static __device__ __forceinline__ unsigned short f2bfc(float f){
  union{float f; unsigned u;} c; c.f = f;
  return (unsigned short)((c.u + 0x8000u) >> 16);
}
static __device__ __forceinline__ unsigned pk2bf(float a, float b){
  union{float f; unsigned u;} ca, cb; ca.f=a; cb.f=b;
  return __builtin_amdgcn_perm(cb.u + 0x8000u, ca.u + 0x8000u, 0x07060302u);
}
static __device__ __forceinline__ unsigned pk2bft(float a, float b){
  union{float f; unsigned u;} ca, cb; ca.f=a; cb.f=b;
  return __builtin_amdgcn_perm(cb.u, ca.u, 0x07060302u);
}
static __device__ __forceinline__ short8 mk8(unsigned x0, unsigned x1,
                                             unsigned x2, unsigned x3){
  union{ unsigned u[4]; short8 s; } t;
  t.u[0]=x0; t.u[1]=x1; t.u[2]=x2; t.u[3]=x3; return t.s;
}
// v_permlane32_swap_b32: new_x[32:63] = old_y[0:31]; new_y[0:31] = old_x[32:63]
static __device__ __forceinline__ void plswap(unsigned &x, unsigned &y){
  auto r = __builtin_amdgcn_permlane32_swap(x, y, false, false);
  x = (unsigned)r[0]; y = (unsigned)r[1];
}

// ---------------------------------------------------------------------------
// Merged prep: [0,1024) wtrans ; [1024,2048) xhat (stats+normalize fused,
// one row per wave) ; [2048,2096) biasfold.
// ---------------------------------------------------------------------------
__global__ __launch_bounds__(256) void prep_kernel(
  const float* __restrict__ data,
  const float* __restrict__ Wq, const float* __restrict__ Wk,
  const float* __restrict__ Wv, const float* __restrict__ Wo,
  const float* __restrict__ gq, const float* __restrict__ gk, const float* __restrict__ gv,
  const float* __restrict__ blq, const float* __restrict__ blk, const float* __restrict__ blv,
  const float* __restrict__ bpq, const float* __restrict__ bpk, const float* __restrict__ bpv,
  unsigned short* __restrict__ WT, unsigned short* __restrict__ xhat,
  float* __restrict__ bf)
{
  __shared__ unsigned short tile[64][72];
  __shared__ float red[4][64];
  int bid = blockIdx.x, t = threadIdx.x;
  if (bid < 1024){
    // --- weight transpose + cast: WT[z][n][k] = scale_z[k] * W_z[k][n] ---
    int z = bid >> 8, rem = bid & 255;
    int k0 = (rem>>4)*64, n0 = (rem&15)*64;
    const float* W = (z==0)?Wq:(z==1)?Wk:(z==2)?Wv:Wo;
    const float* g = (z==0)?gq:(z==1)?gk:(z==2)?gv:(const float*)0;
    unsigned short* out = WT + ((size_t)z<<20);
    {
      int kr = t>>2, c16 = (t&3)*16;
      float gs = g ? g[k0+kr]*((z==0)?CE_:1.0f) : 1.0f;
      const float* src = W + (size_t)(k0+kr)*D_ + n0 + c16;
      float4 w0 = *(const float4*)(src);
      float4 w1 = *(const float4*)(src+4);
      float4 w2 = *(const float4*)(src+8);
      float4 w3 = *(const float4*)(src+12);
      unsigned* tp = (unsigned*)&tile[kr][c16];
      tp[0]=pk2bf(w0.x*gs,w0.y*gs); tp[1]=pk2bf(w0.z*gs,w0.w*gs);
      tp[2]=pk2bf(w1.x*gs,w1.y*gs); tp[3]=pk2bf(w1.z*gs,w1.w*gs);
      tp[4]=pk2bf(w2.x*gs,w2.y*gs); tp[5]=pk2bf(w2.z*gs,w2.w*gs);
      tp[6]=pk2bf(w3.x*gs,w3.y*gs); tp[7]=pk2bf(w3.z*gs,w3.w*gs);
    }
    __syncthreads();
    {
      int nr = t>>2, kc = (t&3)*16;
      union { uint4 v[2]; unsigned short u[16]; } st;
      #pragma unroll
      for (int i=0;i<16;i++) st.u[i] = tile[kc+i][nr];
      unsigned short* dst = out + (size_t)(n0+nr)*D_ + k0 + kc;
      *(uint4*)(dst)     = st.v[0];
      *(uint4*)(dst + 8) = st.v[1];
    }
  } else if (bid < 2048){
    // --- xhat: one row per wave, stats + normalize + bf16 store ---
    int row = (bid-1024)*4 + (t>>6);
    int l = t & 63;
    const float4* xr = (const float4*)(data + (size_t)row*D_);
    float4 v[4];
    float s = 0.f, ss = 0.f;
    #pragma unroll
    for (int i=0;i<4;i++){
      v[i] = xr[l + 64*i];
      s  += v[i].x+v[i].y+v[i].z+v[i].w;
      ss += v[i].x*v[i].x+v[i].y*v[i].y+v[i].z*v[i].z+v[i].w*v[i].w;
    }
    #pragma unroll
    for (int m=1;m<64;m<<=1){ s += __shfl_xor(s, m, 64); ss += __shfl_xor(ss, m, 64); }
    float me = s*(1.0f/D_);
    float var = ss*(1.0f/D_) - me*me;
    float rs = rsqrtf(var + 1e-5f);
    float nm = -me*rs;
    unsigned short* xo = xhat + (size_t)row*D_;
    #pragma unroll
    for (int i=0;i<4;i++){
      uint2 pk;
      pk.x = pk2bf(fmaf(v[i].x,rs,nm), fmaf(v[i].y,rs,nm));
      pk.y = pk2bf(fmaf(v[i].z,rs,nm), fmaf(v[i].w,rs,nm));
      *(uint2*)(xo + 4*l + 256*i) = pk;
    }
  } else {
    // --- folded bias ---
    int idx = bid - 2048;
    int z = idx >> 4, xb = idx & 15;
    const float* W  = (z==0)?Wq:(z==1)?Wk:Wv;
    const float* bl = (z==0)?blq:(z==1)?blk:blv;
    const float* bp = (z==0)?bpq:(z==1)?bpk:bpv;
    int nl = t & 63, kg = t >> 6;
    int n = xb*64 + nl;
    float acc = 0.f;
    for (int k = kg*256; k < (kg+1)*256; k++)
      acc += bl[k] * W[(size_t)k*D_ + n];
    red[kg][nl] = acc;
    __syncthreads();
    if (t < 64){
      int nn = xb*64 + t;
      float v = red[0][t]+red[1][t]+red[2][t]+red[3][t] + bp[nn];
      bf[z*D_ + nn] = (z==0) ? v*CE_ : v;
    }
  }
}

// ---------------------------------------------------------------------------
// Fused QKV GEMM, grid (32,8,3). 128x128 tile. Both tiles via glds width=16
// (A from precomputed bf16 xhat), unpadded stride-32 LDS.
// ---------------------------------------------------------------------------
__global__ __launch_bounds__(256) void gemm_qkv(
  const unsigned short* __restrict__ xhat,
  const unsigned short* __restrict__ WT,
  const float* __restrict__ biasf,
  unsigned short* __restrict__ qv, unsigned short* __restrict__ kb,
  unsigned short* __restrict__ kT, unsigned short* __restrict__ vT)
{
  int z = blockIdx.z;
  const unsigned short* Bt = WT + ((size_t)z<<20);
  const float* bias = biasf + z*D_;
  unsigned short* oN = (z==0)?qv:(z==1)?kb:(unsigned short*)0;
  unsigned short* oT = (z==0)?(unsigned short*)0:(z==1)?kT:vT;

  __shared__ __align__(16) unsigned short As[128*32];
  __shared__ __align__(16) unsigned short Bs[128*32];
  int tid = threadIdx.x, w = tid>>6, l = tid&63;
  int m0 = blockIdx.x*128, n0 = blockIdx.y*128;
  int wr = (w>>1)*64, wc = (w&1)*64;
  int lr = l&15, qd = l>>4;

  const unsigned short* gA = xhat + (size_t)(m0 + w*32 + (l>>2))*D_ + (l&3)*8;
  const unsigned short* gB = Bt   + (size_t)(n0 + w*32 + (l>>2))*D_ + (l&3)*8;
  unsigned short* lA0 = &As[(w*32)*32];
  unsigned short* lA1 = &As[(w*32+16)*32];
  unsigned short* lB0 = &Bs[(w*32)*32];
  unsigned short* lB1 = &Bs[(w*32+16)*32];

  const f32x4 fz = {0.f,0.f,0.f,0.f};
  f32x4 acc[4][4];
  #pragma unroll
  for (int i=0;i<4;i++)
    #pragma unroll
    for (int j=0;j<4;j++) acc[i][j] = fz;

  for (int kk=0; kk<D_; kk+=32){
    __syncthreads();
    glds16(gA + kk,                 lA0);
    glds16(gA + kk + (size_t)16*D_, lA1);
    glds16(gB + kk,                 lB0);
    glds16(gB + kk + (size_t)16*D_, lB1);
    __syncthreads();
    short8 af[4], bfr[4];
    #pragma unroll
    for (int i=0;i<4;i++) af[i]  = *(const short8*)(As + (wr + i*16 + lr)*32 + qd*8);
    #pragma unroll
    for (int j=0;j<4;j++) bfr[j] = *(const short8*)(Bs + (wc + j*16 + lr)*32 + qd*8);
    #pragma unroll
    for (int i=0;i<4;i++)
      #pragma unroll
      for (int j=0;j<4;j++)
        acc[i][j] = __builtin_amdgcn_mfma_f32_16x16x32_bf16(af[i], bfr[j], acc[i][j], 0, 0, 0);
  }

  #pragma unroll
  for (int j=0;j<4;j++){
    int n = n0 + wc + j*16 + lr;
    float bias_n = bias[n];
    #pragma unroll
    for (int i=0;i<4;i++){
      int mb = m0 + wr + i*16 + qd*4;
      float v0 = acc[i][j][0] + bias_n;
      float v1 = acc[i][j][1] + bias_n;
      float v2 = acc[i][j][2] + bias_n;
      float v3 = acc[i][j][3] + bias_n;
      if (oN){
        oN[(size_t)(mb+0)*D_ + n] = f2bfc(v0);
        oN[(size_t)(mb+1)*D_ + n] = f2bfc(v1);
        oN[(size_t)(mb+2)*D_ + n] = f2bfc(v2);
        oN[(size_t)(mb+3)*D_ + n] = f2bfc(v3);
      }
      if (oT){
        int bb = mb >> 11, sI = mb & (S_-1);
        int hh = n >> 6,  dd = n & 63;
        uint2 pk; pk.x = pk2bf(v0, v1); pk.y = pk2bf(v2, v3);
        *(uint2*)(oT + (size_t)((bb*H_ + hh)*HD_ + dd)*S_ + sI) = pk;
      }
    }
  }
}

// ---------------------------------------------------------------------------
// Out-projection: C = A(bf16) @ WTo^T + bo, f32 to d_out. Both tiles via glds.
// ---------------------------------------------------------------------------
__global__ __launch_bounds__(256) void gemm_out(
  const unsigned short* __restrict__ A,
  const unsigned short* __restrict__ Bt,
  const float* __restrict__ bo,
  float* __restrict__ Cf)
{
  __shared__ __align__(16) unsigned short As[128*32];
  __shared__ __align__(16) unsigned short Bs[128*32];
  int tid = threadIdx.x, w = tid>>6, l = tid&63;
  int m0 = blockIdx.x*128, n0 = blockIdx.y*128;
  int wr = (w>>1)*64, wc = (w&1)*64;
  int lr = l&15, qd = l>>4;

  const unsigned short* gA = A  + (size_t)(m0 + w*32 + (l>>2))*D_ + (l&3)*8;
  const unsigned short* gB = Bt + (size_t)(n0 + w*32 + (l>>2))*D_ + (l&3)*8;
  unsigned short* lA0 = &As[(w*32)*32];
  unsigned short* lA1 = &As[(w*32+16)*32];
  unsigned short* lB0 = &Bs[(w*32)*32];
  unsigned short* lB1 = &Bs[(w*32+16)*32];

  const f32x4 fz = {0.f,0.f,0.f,0.f};
  f32x4 acc[4][4];
  #pragma unroll
  for (int i=0;i<4;i++)
    #pragma unroll
    for (int j=0;j<4;j++) acc[i][j] = fz;

  for (int kk=0; kk<D_; kk+=32){
    __syncthreads();
    glds16(gA + kk,                 lA0);
    glds16(gA + kk + (size_t)16*D_, lA1);
    glds16(gB + kk,                 lB0);
    glds16(gB + kk + (size_t)16*D_, lB1);
    __syncthreads();
    short8 af[4], bfr[4];
    #pragma unroll
    for (int i=0;i<4;i++) af[i]  = *(const short8*)(As + (wr + i*16 + lr)*32 + qd*8);
    #pragma unroll
    for (int j=0;j<4;j++) bfr[j] = *(const short8*)(Bs + (wc + j*16 + lr)*32 + qd*8);
    #pragma unroll
    for (int i=0;i<4;i++)
      #pragma unroll
      for (int j=0;j<4;j++)
        acc[i][j] = __builtin_amdgcn_mfma_f32_16x16x32_bf16(af[i], bfr[j], acc[i][j], 0, 0, 0);
  }

  #pragma unroll
  for (int j=0;j<4;j++){
    int n = n0 + wc + j*16 + lr;
    float bias_n = bo[n];
    #pragma unroll
    for (int i=0;i<4;i++){
      int mb = m0 + wr + i*16 + qd*4;
      Cf[(size_t)(mb+0)*D_ + n] = acc[i][j][0] + bias_n;
      Cf[(size_t)(mb+1)*D_ + n] = acc[i][j][1] + bias_n;
      Cf[(size_t)(mb+2)*D_ + n] = acc[i][j][2] + bias_n;
      Cf[(size_t)(mb+3)*D_ + n] = acc[i][j][3] + bias_n;
    }
  }
}

// ---------------------------------------------------------------------------
// Fused double Hopfield attention, kt-split. Grid (64,16), 256 threads.
// Wave (wq = w&1, wk = w>>1): wq = 32-row q-subtile, wk = 64-wide kt half.
// Superstep stages K[128][64] + V^T[64][128] (32 KB) via glds with
// pre-swizzled global source; each wave computes its own 64-k tile.
// Partials combined across wk pairs in LDS at phase boundaries.
// ---------------------------------------------------------------------------
__global__ __launch_bounds__(256, 4) void attn_fused(
  unsigned short* __restrict__ QO,
  const unsigned short* __restrict__ K,
  const unsigned short* __restrict__ KT,
  const unsigned short* __restrict__ VT)
{
  int qt = blockIdx.x;           // 0..63 -> 64 q-rows
  int h  = blockIdx.y;           // 0..15
  int b  = qt >> 5;
  int bh = b*H_ + h;
  int tid = threadIdx.x, w = tid>>6, l = tid&63;
  int wq = w & 1, wk = w >> 1;
  int lq = l & 31, hi = l >> 5;
  int swzr = (lq & 7) << 3;

  __shared__ __align__(16) unsigned short smem[16384];  // 32 KB
  unsigned short* sK = smem;          // [128][64] shorts
  unsigned short* sV = smem + 8192;   // [64][128] shorts

  const f32x16 fz16 = {0.f,0.f,0.f,0.f,0.f,0.f,0.f,0.f,
                       0.f,0.f,0.f,0.f,0.f,0.f,0.f,0.f};

  // ---- initial Q fragments (B-frag: k = hi*8+i, col = lq) ----
  const unsigned short* Qb = QO + (size_t)(qt*64 + wq*32 + lq)*D_ + h*64;
  short8 qf[4];
  #pragma unroll
  for (int d=0; d<4; d++) qf[d] = *(const short8*)(Qb + d*16 + hi*8);

  const unsigned short* Khead = K + (size_t)(b*S_)*D_ + h*64;
  const unsigned short* Vh0 = KT + (size_t)bh*HD_*S_;
  const unsigned short* Vh1 = VT + (size_t)bh*HD_*S_;

  // ---- staging geometry (pre-swizzled global sources, linear LDS) ----
  // K seg j (this wave): rows (w*4+j)*8 + (l>>3), col ((l&7)*8)^((l>>3&7)*8)
  // V seg j: rows (w*4)*4 + j*4 + (l>>4), col ((l&15)*8)^((row&7)*8)
  int seg = w*4;
  int kcol = ((l&7)*8) ^ (((l>>3)&7)*8);
  const unsigned short* gKb = Khead + (size_t)(seg*8 + (l>>3))*D_ + kcol;
  int vrE = seg*4 + (l>>4);                      // rows for j=0 (j=2: +8)
  int vcE = ((l&15)*8) ^ (((l>>4)&7)*8);
  int vcO = ((l&15)*8) ^ ((((l>>4)+4)&7)*8);     // j odd: row&7 = 4+(l>>4)

  unsigned short* lK0 = sK + (seg+0)*512;
  unsigned short* lK1 = sK + (seg+1)*512;
  unsigned short* lK2 = sK + (seg+2)*512;
  unsigned short* lK3 = sK + (seg+3)*512;
  unsigned short* lV0 = sV + (seg+0)*512;
  unsigned short* lV1 = sV + (seg+1)*512;
  unsigned short* lV2 = sV + (seg+2)*512;
  unsigned short* lV3 = sV + (seg+3)*512;

  #pragma unroll 1
  for (int phase=0; phase<2; phase++){
    const unsigned short* Vhead = phase ? Vh1 : Vh0;
    const unsigned short* gK  = gKb;
    const unsigned short* gV0 = Vhead + (size_t)(vrE  )*S_ + vcE;
    const unsigned short* gV1 = Vhead + (size_t)(vrE+4)*S_ + vcO;

    f32x16 oacc0 = fz16, oacc1 = fz16;
    float den = 0.f;

    #pragma unroll 1
    for (int ss=0; ss<16; ss++){
      __syncthreads();                 // prior readers done with smem
      glds16(gK,          lK0);
      glds16(gK +  8*D_,  lK1);
      glds16(gK + 16*D_,  lK2);
      glds16(gK + 24*D_,  lK3);
      glds16(gV0,         lV0);
      glds16(gV1,         lV1);
      glds16(gV0 + 8*S_,  lV2);
      glds16(gV1 + 8*S_,  lV3);
      __syncthreads();                 // drains vmcnt -> tiles visible
      gK  += 128*D_;
      gV0 += 128;
      gV1 += 128;

      // --- QK^T on this wave's 64-k tile: S^T[s][q] ---
      f32x16 sc0 = fz16, sc1 = fz16;
      __builtin_amdgcn_s_setprio(1);
      #pragma unroll
      for (int d4=0; d4<4; d4++){
        int rc = (d4*16 + hi*8) ^ swzr;
        short8 ka0 = *(const short8*)(&sK[(size_t)(wk*64 + lq     )*64 + rc]);
        short8 ka1 = *(const short8*)(&sK[(size_t)(wk*64 + lq + 32)*64 + rc]);
        sc0 = __builtin_amdgcn_mfma_f32_32x32x16_bf16(ka0, qf[d4], sc0, 0,0,0);
        sc1 = __builtin_amdgcn_mfma_f32_32x32x16_bf16(ka1, qf[d4], sc1, 0,0,0);
      }
      __builtin_amdgcn_s_setprio(0);

      // --- exp2, VALU denominator, in-register P->B-frag (T12) ---
      float p0[16], p1[16];
      #pragma unroll
      for (int i=0;i<16;i++){
        p0[i] = __builtin_amdgcn_exp2f(sc0[i]);
        p1[i] = __builtin_amdgcn_exp2f(sc1[i]);
      }
      {
        float t0 = ((p0[0]+p0[1])+(p0[2]+p0[3])) + ((p0[4]+p0[5])+(p0[6]+p0[7]));
        float t1 = ((p0[8]+p0[9])+(p0[10]+p0[11])) + ((p0[12]+p0[13])+(p0[14]+p0[15]));
        float t2 = ((p1[0]+p1[1])+(p1[2]+p1[3])) + ((p1[4]+p1[5])+(p1[6]+p1[7]));
        float t3 = ((p1[8]+p1[9])+(p1[10]+p1[11])) + ((p1[12]+p1[13])+(p1[14]+p1[15]));
        den += (t0+t1)+(t2+t3);
      }
      short8 pf[4];
      {
        unsigned a0,a1,b0,b1;
        a0=pk2bft(p0[0],p0[1]);   a1=pk2bft(p0[2],p0[3]);
        b0=pk2bft(p0[4],p0[5]);   b1=pk2bft(p0[6],p0[7]);
        plswap(a0,b0); plswap(a1,b1);
        pf[0] = mk8(a0,a1,b0,b1);
        a0=pk2bft(p0[8],p0[9]);   a1=pk2bft(p0[10],p0[11]);
        b0=pk2bft(p0[12],p0[13]); b1=pk2bft(p0[14],p0[15]);
        plswap(a0,b0); plswap(a1,b1);
        pf[1] = mk8(a0,a1,b0,b1);
        a0=pk2bft(p1[0],p1[1]);   a1=pk2bft(p1[2],p1[3]);
        b0=pk2bft(p1[4],p1[5]);   b1=pk2bft(p1[6],p1[7]);
        plswap(a0,b0); plswap(a1,b1);
        pf[2] = mk8(a0,a1,b0,b1);
        a0=pk2bft(p1[8],p1[9]);   a1=pk2bft(p1[10],p1[11]);
        b0=pk2bft(p1[12],p1[13]); b1=pk2bft(p1[14],p1[15]);
        plswap(a0,b0); plswap(a1,b1);
        pf[3] = mk8(a0,a1,b0,b1);
      }

      // --- PV: O^T[d][q] += V^T-tile x P (s-cols = this wave's kt half) ---
      __builtin_amdgcn_s_setprio(1);
      #pragma unroll
      for (int ks=0; ks<4; ks++){
        int rc = (wk*64 + ks*16 + hi*8) ^ swzr;
        short8 va0 = *(const short8*)(&sV[(size_t)(lq     )*128 + rc]);
        short8 va1 = *(const short8*)(&sV[(size_t)(lq + 32)*128 + rc]);
        oacc0 = __builtin_amdgcn_mfma_f32_32x32x16_bf16(va0, pf[ks], oacc0, 0,0,0);
        oacc1 = __builtin_amdgcn_mfma_f32_32x32x16_bf16(va1, pf[ks], oacc1, 0,0,0);
      }
      __builtin_amdgcn_s_setprio(0);
    } // ss

    // ---- cross-hi denominator, then cross-wk combine in LDS ----
    den += __shfl_xor(den, 32, 64);

    float* fb = (float*)smem;
    int cb = wq*2112;                      // 33*64 floats per wq region
    __syncthreads();
    if (wk==1){
      #pragma unroll
      for (int i=0;i<16;i++){
        fb[cb + i*64 + l]      = oacc0[i];
        fb[cb + (16+i)*64 + l] = oacc1[i];
      }
      fb[cb + 2048 + l] = den;
    }
    __syncthreads();
    if (wk==0){
      #pragma unroll
      for (int i=0;i<16;i++){
        oacc0[i] += fb[cb + i*64 + l];
        oacc1[i] += fb[cb + (16+i)*64 + l];
      }
      den += fb[cb + 2048 + l];
      if (phase==0){
        // q <- (xi K) * CE, converted to B-frags in-register
        float iv = CE_ * __builtin_amdgcn_rcpf(den);
        unsigned a0,a1,b0,b1;
        a0=pk2bf(oacc0[0]*iv, oacc0[1]*iv);   a1=pk2bf(oacc0[2]*iv, oacc0[3]*iv);
        b0=pk2bf(oacc0[4]*iv, oacc0[5]*iv);   b1=pk2bf(oacc0[6]*iv, oacc0[7]*iv);
        plswap(a0,b0); plswap(a1,b1);
        qf[0] = mk8(a0,a1,b0,b1);
        a0=pk2bf(oacc0[8]*iv, oacc0[9]*iv);   a1=pk2bf(oacc0[10]*iv, oacc0[11]*iv);
        b0=pk2bf(oacc0[12]*iv, oacc0[13]*iv); b1=pk2bf(oacc0[14]*iv, oacc0[15]*iv);
        plswap(a0,b0); plswap(a1,b1);
        qf[1] = mk8(a0,a1,b0,b1);
        a0=pk2bf(oacc1[0]*iv, oacc1[1]*iv);   a1=pk2bf(oacc1[2]*iv, oacc1[3]*iv);
        b0=pk2bf(oacc1[4]*iv, oacc1[5]*iv);   b1=pk2bf(oacc1[6]*iv, oacc1[7]*iv);
        plswap(a0,b0); plswap(a1,b1);
        qf[2] = mk8(a0,a1,b0,b1);
        a0=pk2bf(oacc1[8]*iv, oacc1[9]*iv);   a1=pk2bf(oacc1[10]*iv, oacc1[11]*iv);
        b0=pk2bf(oacc1[12]*iv, oacc1[13]*iv); b1=pk2bf(oacc1[14]*iv, oacc1[15]*iv);
        plswap(a0,b0); plswap(a1,b1);
        qf[3] = mk8(a0,a1,b0,b1);
        // share updated q-frags with the wk=1 partner wave
        unsigned short* qsh = smem + 12288 + wq*2048;
        #pragma unroll
        for (int d=0; d<4; d++)
          *(short8*)(qsh + d*512 + l*8) = qf[d];
      } else {
        float iv = __builtin_amdgcn_rcpf(den);
        // C row = (r&3)+8*(r>>2)+4*hi -> d = g*8 + hi*4 + {0..3}
        unsigned short* Ob = QO + (size_t)(qt*64 + wq*32 + lq)*D_ + h*64 + hi*4;
        #pragma unroll
        for (int g=0; g<4; g++){
          uint2 pk;
          pk.x = pk2bf(oacc0[4*g+0]*iv, oacc0[4*g+1]*iv);
          pk.y = pk2bf(oacc0[4*g+2]*iv, oacc0[4*g+3]*iv);
          *(uint2*)(Ob + g*8) = pk;
          pk.x = pk2bf(oacc1[4*g+0]*iv, oacc1[4*g+1]*iv);
          pk.y = pk2bf(oacc1[4*g+2]*iv, oacc1[4*g+3]*iv);
          *(uint2*)(Ob + 32 + g*8) = pk;
        }
      }
    }
    __syncthreads();
    if (phase==0 && wk==1){
      unsigned short* qsh = smem + 12288 + wq*2048;
      #pragma unroll
      for (int d=0; d<4; d++)
        qf[d] = *(const short8*)(qsh + d*512 + l*8);
    }
  } // phase
}

// ---------------------------------------------------------------------------
extern "C" void kernel_launch(void* const* d_in, const int* in_sizes, int n_in,
                              void* d_out, int out_size, void* d_ws, size_t ws_size,
                              hipStream_t stream){
  const float* data = (const float*)d_in[0];
  const float* g_k  = (const float*)d_in[1];
  const float* b_k  = (const float*)d_in[2];
  const float* g_q  = (const float*)d_in[3];
  const float* b_q  = (const float*)d_in[4];
  const float* g_v  = (const float*)d_in[5];
  const float* b_v  = (const float*)d_in[6];
  const float* Wq   = (const float*)d_in[7];
  const float* bq   = (const float*)d_in[8];
  const float* Wk   = (const float*)d_in[9];
  const float* bk   = (const float*)d_in[10];
  const float* Wv   = (const float*)d_in[11];
  const float* bv   = (const float*)d_in[12];
  const float* Wo   = (const float*)d_in[13];
  const float* bo   = (const float*)d_in[14];
  float* out = (float*)d_out;

  char* ws = (char*)d_ws;
  const size_t MB = (size_t)1<<20;
  unsigned short* q    = (unsigned short*)(ws);
  unsigned short* kb   = (unsigned short*)(ws + 8*MB);
  unsigned short* WT   = (unsigned short*)(ws + 16*MB);
  unsigned short* WTo  = WT + ((size_t)3<<20);
  unsigned short* xhat = (unsigned short*)(ws + 24*MB);
  float*          bfld = (float*)(ws + 32*MB);
  unsigned short* vT   = (unsigned short*)d_out;
  unsigned short* kT   = (unsigned short*)((char*)d_out + 8*MB);

  dim3 gb(256);
  prep_kernel<<<dim3(2096), gb, 0, stream>>>(data,
                                             Wq, Wk, Wv, Wo, g_q, g_k, g_v,
                                             b_q, b_k, b_v, bq, bk, bv,
                                             WT, xhat, bfld);
  gemm_qkv<<<dim3(32,8,3), gb, 0, stream>>>(xhat, WT, bfld, q, kb, kT, vT);
  attn_fused<<<dim3(64, H_), gb, 0, stream>>>(q, kb, kT, vT);
  gemm_out<<<dim3(32,8), gb, 0, stream>>>(q, WTo, bo, out);
}